// Round 5
// baseline (115.246 us; speedup 1.0000x reference)
//
#include <hip/hip_runtime.h>

// SlidingWindowPyramidAttention — all convs + bilinear-attention as bf16 MFMA.
// B=4, C=256, H=W=64, ws=8 -> 256 windows x 64 positions; NH=8, HD=32, NL=3, NP=4.
//
// MFMA convention (HW-verified r3/r4): mfma(X,Y,acc) -> D[m][n];
//   X-frag: lane holds X[m = mtile+(lane&15)][k = ks*32+(lane>>4)*8 + 0..7]
//   Y-frag: lane holds Y[k same slice][n = ntile+(lane&15)]  (8 elems along k)
//   D-frag: col(lane&15) = n, row = mtile + (lane>>4)*4 + r
//
// k_attn phases per level:
//   stage vsT[s][c] bf16  ->  vp GEMM (m=s,n=o) -> VlT[o][s] bf16
//   -> 4x head-pairs: build P f32 (atomicAdd) -> cvt bf16 -> attn GEMM (m=c,n=s)
//   accumulate attn in regs across levels; then op GEMM (m=o,n=s) -> out.

#define CC   256
#define CH   128
#define NPT  4
#define NLV  3
#define SS   64
#define NWIN 256

#define QT_PAD  264   // qT row pitch (bf16)
#define HT_PAD  136   // hT row pitch (bf16)
#define AW_PAD  100   // awS row pitch (f32)
#define VST_PAD 264   // vsT row pitch (bf16)
#define VLT_PAD 72    // VlT row pitch (bf16)
#define PF_PAD  68    // Pf32 row pitch (f32)
#define PB_PAD  72    // Pb row pitch (bf16)

// LDS byte offsets, k_attn
#define OFF_VST  0
#define OFF_VLT  33792                  // 64*264*2
#define OFF_PF   (33792 + 36864)        // + 256*72*2
#define OFF_PB   (33792 + 36864 + 34816)// + 2*64*68*4
#define LDS2_TOT (33792 + 36864 + 34816 + 36864)  // 142336

// bf16 weight pool offsets (elements) in d_ws after PXY+A
#define W_SO1 0
#define W_AW1 32768
#define W_SO2 65536
#define W_AW2 90112
#define W_VP  102400
#define W_OP  167936
#define W_TOT 233472

typedef short bf16x8 __attribute__((ext_vector_type(8)));
typedef short bf16x4 __attribute__((ext_vector_type(4)));
typedef float f32x4  __attribute__((ext_vector_type(4)));

__device__ __forceinline__ int rfl(int x) { return __builtin_amdgcn_readfirstlane(x); }

__device__ __forceinline__ unsigned short f2bf(float f) {
    unsigned u = __builtin_bit_cast(unsigned, f);
    u += 0x7FFFu + ((u >> 16) & 1u);           // RNE
    return (unsigned short)(u >> 16);
}

__device__ __forceinline__ bf16x8 pack8(const float* v) {
    bf16x8 r;
    #pragma unroll
    for (int i = 0; i < 8; i++) r[i] = (short)f2bf(v[i]);
    return r;
}

__device__ __forceinline__ int xcd_swz(int bid) {   // 256 % 8 == 0: bijective
    return ((bid & 7) << 5) | (bid >> 3);
}

// ---------------------------------------------------------------------------
// K0: fp32 -> bf16 weight conversion (idempotent).
// ---------------------------------------------------------------------------
struct WPack {
    const float *s0, *s1, *s2, *s3, *s4, *s5;
    unsigned short* d;
};
__global__ __launch_bounds__(256) void k_cvt(WPack p) {
    int i = (blockIdx.x * 256 + threadIdx.x) * 8;
    if (i >= W_TOT) return;
    const float* src; int off;
    if      (i < W_AW1) { src = p.s0; off = W_SO1; }
    else if (i < W_SO2) { src = p.s1; off = W_AW1; }
    else if (i < W_AW2) { src = p.s2; off = W_SO2; }
    else if (i < W_VP)  { src = p.s3; off = W_AW2; }
    else if (i < W_OP)  { src = p.s4; off = W_VP;  }
    else                { src = p.s5; off = W_OP;  }
    const float* s = src + (i - off);
    float4 a = *(const float4*)s;
    float4 b = *(const float4*)(s + 4);
    float tmp[8] = {a.x, a.y, a.z, a.w, b.x, b.y, b.z, b.w};
    *(bf16x8*)(p.d + i) = pack8(tmp);
}

// ---------------------------------------------------------------------------
// K1: offset + attention-weight heads (round-4 verified) + XCD swizzle.
// ---------------------------------------------------------------------------
__global__ __launch_bounds__(256, 1) void k_heads(
    const float* __restrict__ query,
    const unsigned short* __restrict__ wso1, const float* __restrict__ so_b1,
    const float* __restrict__ so_g,  const float* __restrict__ so_be,
    const unsigned short* __restrict__ wso2, const float* __restrict__ so_b2,
    const unsigned short* __restrict__ waw1, const float* __restrict__ aw_b1,
    const float* __restrict__ aw_g,  const float* __restrict__ aw_be,
    const unsigned short* __restrict__ waw2, const float* __restrict__ aw_b2,
    float2* __restrict__ PXY, float* __restrict__ A)
{
    extern __shared__ char smem[];
    unsigned short* qT   = (unsigned short*)smem;                       // [64][264]
    unsigned short* hTso = (unsigned short*)(smem + SS * QT_PAD * 2);   // [64][136]
    unsigned short* hTaw = hTso + SS * HT_PAD;                          // [64][136]
    float* awS = (float*)(smem + SS * QT_PAD * 2 + 2 * SS * HT_PAD * 2);// [64][100]

    const int bw = xcd_swz(blockIdx.x);
    const int b  = bw >> 6;
    const int wy = (bw >> 3) & 7;
    const int wx = bw & 7;
    const int t  = threadIdx.x;
    const int lane = t & 63;
    const int g  = rfl(t >> 6);
    const int kc = (lane >> 4) * 8;
    const int srow = (lane >> 3) * 64 + (lane & 7);

    {
        const float* qb = query + (size_t)b * CC * 4096 + wy * 8 * 64 + wx * 8;
        for (int it = 0; it < 8; it++) {
            int cg = g * 8 + it;
            float tmp[8];
            #pragma unroll
            for (int j = 0; j < 8; j++)
                tmp[j] = qb[(size_t)(cg * 8 + j) * 4096 + srow];
            *(bf16x8*)(qT + lane * QT_PAD + cg * 8) = pack8(tmp);
        }
    }
    __syncthreads();

    f32x4 accS[2][4], accA[2][4];
    #pragma unroll
    for (int mt = 0; mt < 2; mt++)
        #pragma unroll
        for (int nt = 0; nt < 4; nt++) {
            accS[mt][nt] = (f32x4){0.f, 0.f, 0.f, 0.f};
            accA[mt][nt] = (f32x4){0.f, 0.f, 0.f, 0.f};
        }
    for (int ks = 0; ks < 8; ks++) {
        const int c = ks * 32 + kc;
        bf16x8 bq[4];
        #pragma unroll
        for (int nt = 0; nt < 4; nt++)
            bq[nt] = *(const bf16x8*)(qT + (nt * 16 + (lane & 15)) * QT_PAD + c);
        #pragma unroll
        for (int mt = 0; mt < 2; mt++) {
            const int o = g * 32 + mt * 16 + (lane & 15);
            bf16x8 aS = *(const bf16x8*)(wso1 + (size_t)o * CC + c);
            bf16x8 aA = *(const bf16x8*)(waw1 + (size_t)o * CC + c);
            #pragma unroll
            for (int nt = 0; nt < 4; nt++) {
                accS[mt][nt] = __builtin_amdgcn_mfma_f32_16x16x32_bf16(aS, bq[nt], accS[mt][nt], 0, 0, 0);
                accA[mt][nt] = __builtin_amdgcn_mfma_f32_16x16x32_bf16(aA, bq[nt], accA[mt][nt], 0, 0, 0);
            }
        }
    }

    auto gn_store = [&](f32x4 (&acc)[2][4], const float* B1, const float* G,
                        const float* Be, unsigned short* hT) {
        #pragma unroll
        for (int mt = 0; mt < 2; mt++) {
            const int c2b = g * 32 + mt * 16 + ((lane >> 4) << 2);
            float4 bv = *(const float4*)(B1 + c2b);
            float s = 0.f, q = 0.f;
            #pragma unroll
            for (int nt = 0; nt < 4; nt++)
                #pragma unroll
                for (int r = 0; r < 4; r++) {
                    float v = acc[mt][nt][r] + ((const float*)&bv)[r];
                    acc[mt][nt][r] = v;
                    s += v; q += v * v;
                }
            #pragma unroll
            for (int off = 1; off < 64; off <<= 1) {
                s += __shfl_xor(s, off, 64);
                q += __shfl_xor(q, off, 64);
            }
            const float mu = s * (1.f / 1024.f);
            const float rs = rsqrtf(q * (1.f / 1024.f) - mu * mu + 1e-5f);
            float4 Gv  = *(const float4*)(G + c2b);
            float4 Bev = *(const float4*)(Be + c2b);
            #pragma unroll
            for (int nt = 0; nt < 4; nt++) {
                int ss = nt * 16 + (lane & 15);
                bf16x4 pk;
                #pragma unroll
                for (int r = 0; r < 4; r++) {
                    float val = (acc[mt][nt][r] - mu) * rs * ((const float*)&Gv)[r]
                                + ((const float*)&Bev)[r];
                    pk[r] = (short)f2bf(fmaxf(val, 0.f));
                }
                *(bf16x4*)(hT + ss * HT_PAD + c2b) = pk;
            }
        }
    };
    gn_store(accS, so_b1, so_g, so_be, hTso);
    gn_store(accA, aw_b1, aw_g, aw_be, hTaw);
    __syncthreads();

    {   // conv2-so -> PXY
        f32x4 acc2[3][4];
        #pragma unroll
        for (int mt = 0; mt < 3; mt++)
            #pragma unroll
            for (int nt = 0; nt < 4; nt++) acc2[mt][nt] = (f32x4){0.f, 0.f, 0.f, 0.f};
        for (int ks = 0; ks < 4; ks++) {
            const int c = ks * 32 + kc;
            bf16x8 bh[4];
            #pragma unroll
            for (int nt = 0; nt < 4; nt++)
                bh[nt] = *(const bf16x8*)(hTso + (nt * 16 + (lane & 15)) * HT_PAD + c);
            #pragma unroll
            for (int mt = 0; mt < 3; mt++) {
                const int o = g * 48 + mt * 16 + (lane & 15);
                bf16x8 af = *(const bf16x8*)(wso2 + (size_t)o * CH + c);
                #pragma unroll
                for (int nt = 0; nt < 4; nt++)
                    acc2[mt][nt] = __builtin_amdgcn_mfma_f32_16x16x32_bf16(af, bh[nt], acc2[mt][nt], 0, 0, 0);
            }
        }
        #pragma unroll
        for (int mt = 0; mt < 3; mt++) {
            const int o_base = g * 48 + mt * 16 + ((lane >> 4) << 2);
            float4 sb = *(const float4*)(so_b2 + o_base);
            #pragma unroll
            for (int nt = 0; nt < 4; nt++) {
                const int s = nt * 16 + (lane & 15);
                const float refx = (s & 7) * (1.f / 7.f);
                const float refy = (s >> 3) * (1.f / 7.f);
                auto mkp = [](float refc, float oc) {
                    float lc = fminf(fmaxf(refc + oc * 0.125f, 0.f), 1.f);
                    return fminf(fmaxf(lc * 8.f - 0.5f, 0.f), 7.f);
                };
                float4 out4;
                out4.x = mkp(refx, acc2[mt][nt][0] + sb.x);
                out4.y = mkp(refy, acc2[mt][nt][1] + sb.y);
                out4.z = mkp(refx, acc2[mt][nt][2] + sb.z);
                out4.w = mkp(refy, acc2[mt][nt][3] + sb.w);
                *(float4*)(PXY + (size_t)bw * 6144 + s * 96 + (o_base >> 1)) = out4;
            }
        }
    }

    {   // conv2-aw -> awS logits
        for (int mm = 0; mm < 2; mm++) {
            const int mtile = g + mm * 4;
            if (mtile >= 6) break;
            f32x4 acc3[4];
            #pragma unroll
            for (int nt = 0; nt < 4; nt++) acc3[nt] = (f32x4){0.f, 0.f, 0.f, 0.f};
            for (int ks = 0; ks < 4; ks++) {
                const int c = ks * 32 + kc;
                const int o = mtile * 16 + (lane & 15);
                bf16x8 af = *(const bf16x8*)(waw2 + (size_t)o * CH + c);
                #pragma unroll
                for (int nt = 0; nt < 4; nt++) {
                    bf16x8 bh = *(const bf16x8*)(hTaw + (nt * 16 + (lane & 15)) * HT_PAD + c);
                    acc3[nt] = __builtin_amdgcn_mfma_f32_16x16x32_bf16(af, bh, acc3[nt], 0, 0, 0);
                }
            }
            const int o_base = mtile * 16 + ((lane >> 4) << 2);
            float4 ab = *(const float4*)(aw_b2 + o_base);
            #pragma unroll
            for (int nt = 0; nt < 4; nt++) {
                const int s = nt * 16 + (lane & 15);
                float4 o4;
                o4.x = acc3[nt][0] + ab.x;
                o4.y = acc3[nt][1] + ab.y;
                o4.z = acc3[nt][2] + ab.z;
                o4.w = acc3[nt][3] + ab.w;
                *(float4*)(awS + s * AW_PAD + o_base) = o4;
            }
        }
    }
    __syncthreads();

    for (int task = t; task < 512; task += 256) {   // softmax over 12 per (s,h)
        const int s = task >> 3, h = task & 7;
        const float* row = awS + s * AW_PAD + h * 12;
        float4 r0 = *(const float4*)row;
        float4 r1 = *(const float4*)(row + 4);
        float4 r2 = *(const float4*)(row + 8);
        float v[12] = {r0.x, r0.y, r0.z, r0.w, r1.x, r1.y, r1.z, r1.w,
                       r2.x, r2.y, r2.z, r2.w};
        float m = v[0];
        #pragma unroll
        for (int j = 1; j < 12; j++) m = fmaxf(m, v[j]);
        float sum = 0.f;
        #pragma unroll
        for (int j = 0; j < 12; j++) { v[j] = __expf(v[j] - m); sum += v[j]; }
        float rinv = 1.f / sum;
        float* dst = A + (size_t)bw * 6144 + s * 96 + h * 12;
        float4 w0 = {v[0] * rinv, v[1] * rinv, v[2] * rinv, v[3] * rinv};
        float4 w1 = {v[4] * rinv, v[5] * rinv, v[6] * rinv, v[7] * rinv};
        float4 w2 = {v[8] * rinv, v[9] * rinv, v[10] * rinv, v[11] * rinv};
        *(float4*)dst = w0;
        *(float4*)(dst + 4) = w1;
        *(float4*)(dst + 8) = w2;
    }
}

// ---------------------------------------------------------------------------
// K2: vp GEMM + P-matrix attention GEMM + op GEMM.
// ---------------------------------------------------------------------------
__global__ __launch_bounds__(256, 1) void k_attn(
    const float* __restrict__ values,
    const unsigned short* __restrict__ wvp, const float* __restrict__ vp_b,
    const unsigned short* __restrict__ wop, const float* __restrict__ op_b,
    const float* __restrict__ lemb,
    const float2* __restrict__ PXY, const float* __restrict__ A,
    float* __restrict__ outp)
{
    extern __shared__ char smem[];
    unsigned short* vsT = (unsigned short*)(smem + OFF_VST);  // [64][264] bf16
    unsigned short* VlT = (unsigned short*)(smem + OFF_VLT);  // [256][72] bf16
    float*          Pf  = (float*)(smem + OFF_PF);            // [2][64][68] f32
    unsigned short* Pb  = (unsigned short*)(smem + OFF_PB);   // [2buf][2][64][72] bf16

    const int bw = xcd_swz(blockIdx.x);
    const int b  = bw >> 6;
    const int wy = (bw >> 3) & 7;
    const int wx = bw & 7;
    const int t  = threadIdx.x;
    const int lane = t & 63;
    const int g  = rfl(t >> 6);
    const int kc = (lane >> 4) * 8;
    const int srow = (lane >> 3) * 64 + (lane & 7);

    f32x4 accA[8][2];   // attn out, persistent across levels: [head][mtile]
    #pragma unroll
    for (int h = 0; h < 8; h++)
        #pragma unroll
        for (int mt = 0; mt < 2; mt++) accA[h][mt] = (f32x4){0.f, 0.f, 0.f, 0.f};

    for (int l = 0; l < NLV; l++) {
        // ---- stage vsT[s][c] bf16 (+ level embed)
        {
            const float* vb = values + ((size_t)(b * NLV + l) * CC) * 4096 + wy * 8 * 64 + wx * 8;
            const float* le = lemb + l * CC;
            for (int it = 0; it < 8; it++) {
                int cg = g * 8 + it;
                float tmp[8];
                #pragma unroll
                for (int j = 0; j < 8; j++) {
                    int c = cg * 8 + j;
                    tmp[j] = vb[(size_t)c * 4096 + srow] + le[c];
                }
                *(bf16x8*)(vsT + lane * VST_PAD + cg * 8) = pack8(tmp);
            }
        }
        __syncthreads();

        // ---- vp GEMM (m=s, n=o): D[s][o] -> VlT[o][s] bf16 (+bias)
        {
            f32x4 vacc[4][4];
            #pragma unroll
            for (int mt = 0; mt < 4; mt++)
                #pragma unroll
                for (int nt = 0; nt < 4; nt++) vacc[mt][nt] = (f32x4){0.f, 0.f, 0.f, 0.f};
            for (int ks = 0; ks < 8; ks++) {
                const int c = ks * 32 + kc;
                bf16x8 aq[4];
                #pragma unroll
                for (int mt = 0; mt < 4; mt++)
                    aq[mt] = *(const bf16x8*)(vsT + (mt * 16 + (lane & 15)) * VST_PAD + c);
                #pragma unroll
                for (int nt = 0; nt < 4; nt++) {
                    const int o = g * 64 + nt * 16 + (lane & 15);
                    bf16x8 wf = *(const bf16x8*)(wvp + (size_t)o * CC + c);
                    #pragma unroll
                    for (int mt = 0; mt < 4; mt++)
                        vacc[mt][nt] = __builtin_amdgcn_mfma_f32_16x16x32_bf16(
                            aq[mt], wf, vacc[mt][nt], 0, 0, 0);
                }
            }
            #pragma unroll
            for (int nt = 0; nt < 4; nt++) {
                const int o = g * 64 + nt * 16 + (lane & 15);
                const float bias = vp_b[o];
                #pragma unroll
                for (int mt = 0; mt < 4; mt++) {
                    bf16x4 pk;
                    #pragma unroll
                    for (int r = 0; r < 4; r++) pk[r] = (short)f2bf(vacc[mt][nt][r] + bias);
                    *(bf16x4*)(VlT + o * VLT_PAD + mt * 16 + ((lane >> 4) << 2)) = pk;
                }
            }
        }
        __syncthreads();

        // ---- 4 head-pairs: build P (f32 atomic) -> bf16 -> attn GEMM
        #pragma unroll
        for (int hp = 0; hp < 4; hp++) {
            // zero Pf: 2*64*68 f32 = 2176 float4
            for (int i = t; i < 2176; i += 256)
                ((float4*)Pf)[i] = (float4){0.f, 0.f, 0.f, 0.f};
            __syncthreads();
            // build: 512 tasks = (hh, s, p)
            for (int task = t; task < 512; task += 256) {
                const int p  = task & 3;
                const int s  = (task >> 2) & 63;
                const int hh = task >> 8;
                const size_t base = (size_t)bw * 6144 + s * 96 + (hp * 2 + hh) * 12 + l * 4 + p;
                float2 pxy = PXY[base];
                float  a   = A[base];
                float x0f = floorf(pxy.x), y0f = floorf(pxy.y);
                float fx = pxy.x - x0f, fy = pxy.y - y0f;
                int x0 = (int)x0f, y0 = (int)y0f;
                int x1 = min(x0 + 1, 7), y1 = min(y0 + 1, 7);
                float* prow = Pf + (hh * 64 + s) * PF_PAD;
                atomicAdd(prow + y0 * 8 + x0, a * (1.f - fx) * (1.f - fy));
                atomicAdd(prow + y0 * 8 + x1, a * fx * (1.f - fy));
                atomicAdd(prow + y1 * 8 + x0, a * (1.f - fx) * fy);
                atomicAdd(prow + y1 * 8 + x1, a * fx * fy);
            }
            __syncthreads();
            // cvt -> Pb[hp&1]
            unsigned short* pb = Pb + (hp & 1) * (2 * 64 * PB_PAD);
            for (int q = t; q < 1024; q += 256) {
                const int hh = q >> 9, rem = q & 511;
                const int s = rem >> 3, cb = (rem & 7) * 8;
                const float* src = Pf + (hh * 64 + s) * PF_PAD + cb;
                float4 a0 = *(const float4*)src;
                float4 a1 = *(const float4*)(src + 4);
                float tmp[8] = {a0.x, a0.y, a0.z, a0.w, a1.x, a1.y, a1.z, a1.w};
                *(bf16x8*)(pb + (hh * 64 + s) * PB_PAD + cb) = pack8(tmp);
            }
            __syncthreads();
            // attn GEMM: m = c (head channels), n = s (wave g: s-block g*16)
            #pragma unroll
            for (int hh = 0; hh < 2; hh++) {
                #pragma unroll
                for (int ks = 0; ks < 2; ks++) {
                    const int sp = ks * 32 + kc;
                    bf16x8 bfr = *(const bf16x8*)(pb + (hh * 64 + g * 16 + (lane & 15)) * PB_PAD + sp);
                    #pragma unroll
                    for (int mt = 0; mt < 2; mt++) {
                        const int c = (hp * 2 + hh) * 32 + mt * 16 + (lane & 15);
                        bf16x8 afr = *(const bf16x8*)(VlT + c * VLT_PAD + sp);
                        accA[hp * 2 + hh][mt] = __builtin_amdgcn_mfma_f32_16x16x32_bf16(
                            afr, bfr, accA[hp * 2 + hh][mt], 0, 0, 0);
                    }
                }
            }
        }
    }

    // ---- write attn out -> vsT[s][c] bf16 (D: col = s = g*16+(lane&15))
    {
        const int s = g * 16 + (lane & 15);
        #pragma unroll
        for (int h = 0; h < 8; h++)
            #pragma unroll
            for (int mt = 0; mt < 2; mt++) {
                bf16x4 pk;
                #pragma unroll
                for (int r = 0; r < 4; r++) pk[r] = (short)f2bf(accA[h][mt][r]);
                *(bf16x4*)(vsT + s * VST_PAD + h * 32 + mt * 16 + ((lane >> 4) << 2)) = pk;
            }
    }
    __syncthreads();

    // ---- op GEMM (m=o, n=s) + bias + window-reverse store
    {
        f32x4 acc[4][4];
        #pragma unroll
        for (int mt = 0; mt < 4; mt++)
            #pragma unroll
            for (int nt = 0; nt < 4; nt++) acc[mt][nt] = (f32x4){0.f, 0.f, 0.f, 0.f};
        for (int ks = 0; ks < 8; ks++) {
            const int c = ks * 32 + kc;
            bf16x8 bq[4];
            #pragma unroll
            for (int nt = 0; nt < 4; nt++)
                bq[nt] = *(const bf16x8*)(vsT + (nt * 16 + (lane & 15)) * VST_PAD + c);
            #pragma unroll
            for (int mt = 0; mt < 4; mt++) {
                const int o = g * 64 + mt * 16 + (lane & 15);
                bf16x8 af = *(const bf16x8*)(wop + (size_t)o * CC + c);
                #pragma unroll
                for (int nt = 0; nt < 4; nt++)
                    acc[mt][nt] = __builtin_amdgcn_mfma_f32_16x16x32_bf16(
                        af, bq[nt], acc[mt][nt], 0, 0, 0);
            }
        }
        const size_t obase = (size_t)b * CC * 4096 + wy * 8 * 64 + wx * 8;
        #pragma unroll
        for (int mt = 0; mt < 4; mt++)
            #pragma unroll
            for (int nt = 0; nt < 4; nt++)
                #pragma unroll
                for (int r = 0; r < 4; r++) {
                    int o = g * 64 + mt * 16 + (lane >> 4) * 4 + r;
                    int s = nt * 16 + (lane & 15);
                    outp[obase + (size_t)o * 4096 + (s >> 3) * 64 + (s & 7)]
                        = acc[mt][nt][r] + op_b[o];
                }
    }
}

// ---------------------------------------------------------------------------
extern "C" void kernel_launch(void* const* d_in, const int* in_sizes, int n_in,
                              void* d_out, int out_size, void* d_ws, size_t ws_size,
                              hipStream_t stream)
{
    (void)in_sizes; (void)n_in; (void)out_size; (void)ws_size;
    const float* query = (const float*)d_in[0];
    const float* values = (const float*)d_in[2];
    const float* so_w1 = (const float*)d_in[3];
    const float* so_b1 = (const float*)d_in[4];
    const float* so_g  = (const float*)d_in[5];
    const float* so_be = (const float*)d_in[6];
    const float* so_w2 = (const float*)d_in[7];
    const float* so_b2 = (const float*)d_in[8];
    const float* aw_w1 = (const float*)d_in[9];
    const float* aw_b1 = (const float*)d_in[10];
    const float* aw_g  = (const float*)d_in[11];
    const float* aw_be = (const float*)d_in[12];
    const float* aw_w2 = (const float*)d_in[13];
    const float* aw_b2 = (const float*)d_in[14];
    const float* vp_w  = (const float*)d_in[15];
    const float* vp_b  = (const float*)d_in[16];
    const float* op_w  = (const float*)d_in[17];
    const float* op_b  = (const float*)d_in[18];
    const float* lemb  = (const float*)d_in[19];

    float2* PXY = (float2*)d_ws;
    float*  A   = (float*)((char*)d_ws + (size_t)NWIN * 6144 * sizeof(float2));
    unsigned short* WB = (unsigned short*)((char*)d_ws
                        + (size_t)NWIN * 6144 * (sizeof(float2) + sizeof(float)));
    float* outp = (float*)d_out;

    WPack p = {so_w1, aw_w1, so_w2, aw_w2, vp_w, op_w, WB};
    k_cvt<<<dim3((W_TOT / 8 + 255) / 256), dim3(256), 0, stream>>>(p);

    const int lds1 = SS * QT_PAD * 2 + 2 * SS * HT_PAD * 2 + SS * AW_PAD * 4; // 94208
    hipFuncSetAttribute((const void*)k_heads, hipFuncAttributeMaxDynamicSharedMemorySize, lds1);
    hipFuncSetAttribute((const void*)k_attn,  hipFuncAttributeMaxDynamicSharedMemorySize, LDS2_TOT);

    k_heads<<<dim3(NWIN), dim3(256), lds1, stream>>>(
        query, WB + W_SO1, so_b1, so_g, so_be, WB + W_SO2, so_b2,
        WB + W_AW1, aw_b1, aw_g, aw_be, WB + W_AW2, aw_b2, PXY, A);
    k_attn<<<dim3(NWIN), dim3(256), LDS2_TOT, stream>>>(
        values, WB + W_VP, vp_b, WB + W_OP, op_b, lemb, PXY, A, outp);
}

// Round 6
// 100.048 us; speedup vs baseline: 1.1519x; 1.1519x over previous
//
#include <hip/hip_runtime.h>

// SlidingWindowPyramidAttention — MFMA convs + register bilinear gather.
// B=4, C=256, H=W=64, ws=8 -> 256 windows x 64 positions; NH=8, HD=32, NL=3, NP=4.
//
// MFMA convention (HW-verified r3/r4): mfma(X,Y,acc) -> D[m][n];
//   X-frag: lane holds X[m = mtile+(lane&15)][k = ks*32+(lane>>4)*8 + 0..7]
//   Y-frag: lane holds Y[k same slice][n = ntile+(lane&15)]
//   D-frag: col(lane&15) = n, row = mtile + (lane>>4)*4 + r
//
// Occupancy plan: k_heads grid 512 (window x {so,aw}), k_attn grid 768
// (window x level), k_out grid 256 — all <=80KB LDS -> 2 blocks/CU.

#define CC   256
#define CH   128
#define NPT  4
#define NLV  3
#define SS   64
#define NWIN 256

#define QT_PAD  264   // qT row pitch (bf16)
#define HT_PAD  136   // hT row pitch (bf16)
#define AW_PAD  100   // awS row pitch (f32)
#define VST_PAD 264   // vsT row pitch (bf16)
#define VLB_PAD 264   // Vb row pitch (bf16)

// bf16 weight pool offsets (elements) in d_ws after PXY+A
#define W_SO1 0
#define W_AW1 32768
#define W_SO2 65536
#define W_AW2 90112
#define W_VP  102400
#define W_OP  167936
#define W_TOT 233472

// d_ws byte offsets
#define WS_PXY  0
#define WS_A    12582912
#define WS_WB   18874368
#define WS_POUT 19341312   // bf16 [256][3][64][256]

typedef short bf16x8 __attribute__((ext_vector_type(8)));
typedef short bf16x4 __attribute__((ext_vector_type(4)));
typedef float f32x4  __attribute__((ext_vector_type(4)));

__device__ __forceinline__ int rfl(int x) { return __builtin_amdgcn_readfirstlane(x); }

__device__ __forceinline__ unsigned short f2bf(float f) {
    unsigned u = __builtin_bit_cast(unsigned, f);
    u += 0x7FFFu + ((u >> 16) & 1u);           // RNE
    return (unsigned short)(u >> 16);
}
__device__ __forceinline__ float bf2f(short s) {
    unsigned u = ((unsigned)(unsigned short)s) << 16;
    return __builtin_bit_cast(float, u);
}
__device__ __forceinline__ bf16x8 pack8(const float* v) {
    bf16x8 r;
    #pragma unroll
    for (int i = 0; i < 8; i++) r[i] = (short)f2bf(v[i]);
    return r;
}
__device__ __forceinline__ int xcd_swz(int bid) {   // 256 blocks, bijective
    return ((bid & 7) << 5) | (bid >> 3);
}

// ---------------------------------------------------------------------------
// K0: fp32 -> bf16 weight conversion (idempotent).
// ---------------------------------------------------------------------------
struct WPack {
    const float *s0, *s1, *s2, *s3, *s4, *s5;
    unsigned short* d;
};
__global__ __launch_bounds__(256) void k_cvt(WPack p) {
    int i = (blockIdx.x * 256 + threadIdx.x) * 8;
    if (i >= W_TOT) return;
    const float* src; int off;
    if      (i < W_AW1) { src = p.s0; off = W_SO1; }
    else if (i < W_SO2) { src = p.s1; off = W_AW1; }
    else if (i < W_AW2) { src = p.s2; off = W_SO2; }
    else if (i < W_VP)  { src = p.s3; off = W_AW2; }
    else if (i < W_OP)  { src = p.s4; off = W_VP;  }
    else                { src = p.s5; off = W_OP;  }
    const float* s = src + (i - off);
    float4 a = *(const float4*)s;
    float4 b = *(const float4*)(s + 4);
    float tmp[8] = {a.x, a.y, a.z, a.w, b.x, b.y, b.z, b.w};
    *(bf16x8*)(p.d + i) = pack8(tmp);
}

// ---------------------------------------------------------------------------
// K1: heads, split by kind (blockIdx>>8: 0=sampling-offset, 1=attn-weight).
//   LDS: qT[64][264]bf16 33792 + hT[64][136]bf16 17408 + awS[64][100]f32 25600
//        = 76800 B -> 2 blocks/CU.
// ---------------------------------------------------------------------------
__global__ __launch_bounds__(256, 2) void k_heads(
    const float* __restrict__ query,
    const unsigned short* __restrict__ wso1, const float* __restrict__ so_b1,
    const float* __restrict__ so_g,  const float* __restrict__ so_be,
    const unsigned short* __restrict__ wso2, const float* __restrict__ so_b2,
    const unsigned short* __restrict__ waw1, const float* __restrict__ aw_b1,
    const float* __restrict__ aw_g,  const float* __restrict__ aw_be,
    const unsigned short* __restrict__ waw2, const float* __restrict__ aw_b2,
    float2* __restrict__ PXY, float* __restrict__ A)
{
    extern __shared__ char smem[];
    unsigned short* qT = (unsigned short*)smem;                 // [64][264]
    unsigned short* hT = (unsigned short*)(smem + 33792);       // [64][136]
    float* awS = (float*)(smem + 33792 + 17408);                // [64][100]

    const int bid  = blockIdx.x;
    const int kind = bid >> 8;
    const int bw = xcd_swz(bid & 255);
    const int b  = bw >> 6;
    const int wy = (bw >> 3) & 7;
    const int wx = bw & 7;
    const int t  = threadIdx.x;
    const int lane = t & 63;
    const int g  = rfl(t >> 6);
    const int kc = (lane >> 4) * 8;
    const int srow = (lane >> 3) * 64 + (lane & 7);

    const unsigned short* w1 = kind ? waw1 : wso1;
    const float* B1 = kind ? aw_b1 : so_b1;
    const float* G  = kind ? aw_g  : so_g;
    const float* Be = kind ? aw_be : so_be;

    // ---- stage qT[s][c] bf16
    {
        const float* qb = query + (size_t)b * CC * 4096 + wy * 8 * 64 + wx * 8;
        for (int it = 0; it < 8; it++) {
            int cg = g * 8 + it;
            float tmp[8];
            #pragma unroll
            for (int j = 0; j < 8; j++)
                tmp[j] = qb[(size_t)(cg * 8 + j) * 4096 + srow];
            *(bf16x8*)(qT + lane * QT_PAD + cg * 8) = pack8(tmp);
        }
    }
    __syncthreads();

    // ---- conv1 GEMM (256->128), wave g -> rows [g*32,+32)
    f32x4 acc1[2][4];
    #pragma unroll
    for (int mt = 0; mt < 2; mt++)
        #pragma unroll
        for (int nt = 0; nt < 4; nt++) acc1[mt][nt] = (f32x4){0.f, 0.f, 0.f, 0.f};
    for (int ks = 0; ks < 8; ks++) {
        const int c = ks * 32 + kc;
        bf16x8 bq[4];
        #pragma unroll
        for (int nt = 0; nt < 4; nt++)
            bq[nt] = *(const bf16x8*)(qT + (nt * 16 + (lane & 15)) * QT_PAD + c);
        #pragma unroll
        for (int mt = 0; mt < 2; mt++) {
            const int o = g * 32 + mt * 16 + (lane & 15);
            bf16x8 af = *(const bf16x8*)(w1 + (size_t)o * CC + c);
            #pragma unroll
            for (int nt = 0; nt < 4; nt++)
                acc1[mt][nt] = __builtin_amdgcn_mfma_f32_16x16x32_bf16(af, bq[nt], acc1[mt][nt], 0, 0, 0);
        }
    }

    // ---- GN(+bias,ReLU): wave g's mtile mt == GN group 2g+mt (16ch x 64sp)
    #pragma unroll
    for (int mt = 0; mt < 2; mt++) {
        const int c2b = g * 32 + mt * 16 + ((lane >> 4) << 2);
        float4 bv = *(const float4*)(B1 + c2b);
        float s = 0.f, q = 0.f;
        #pragma unroll
        for (int nt = 0; nt < 4; nt++)
            #pragma unroll
            for (int r = 0; r < 4; r++) {
                float v = acc1[mt][nt][r] + ((const float*)&bv)[r];
                acc1[mt][nt][r] = v;
                s += v; q += v * v;
            }
        #pragma unroll
        for (int off = 1; off < 64; off <<= 1) {
            s += __shfl_xor(s, off, 64);
            q += __shfl_xor(q, off, 64);
        }
        const float mu = s * (1.f / 1024.f);
        const float rs = rsqrtf(q * (1.f / 1024.f) - mu * mu + 1e-5f);
        float4 Gv  = *(const float4*)(G + c2b);
        float4 Bev = *(const float4*)(Be + c2b);
        #pragma unroll
        for (int nt = 0; nt < 4; nt++) {
            int ss = nt * 16 + (lane & 15);
            bf16x4 pk;
            #pragma unroll
            for (int r = 0; r < 4; r++) {
                float val = (acc1[mt][nt][r] - mu) * rs * ((const float*)&Gv)[r]
                            + ((const float*)&Bev)[r];
                pk[r] = (short)f2bf(fmaxf(val, 0.f));
            }
            *(bf16x4*)(hT + ss * HT_PAD + c2b) = pk;
        }
    }
    __syncthreads();

    if (!kind) {
        // ---- conv2-so (128->192) -> PXY
        f32x4 acc2[3][4];
        #pragma unroll
        for (int mt = 0; mt < 3; mt++)
            #pragma unroll
            for (int nt = 0; nt < 4; nt++) acc2[mt][nt] = (f32x4){0.f, 0.f, 0.f, 0.f};
        for (int ks = 0; ks < 4; ks++) {
            const int c = ks * 32 + kc;
            bf16x8 bh[4];
            #pragma unroll
            for (int nt = 0; nt < 4; nt++)
                bh[nt] = *(const bf16x8*)(hT + (nt * 16 + (lane & 15)) * HT_PAD + c);
            #pragma unroll
            for (int mt = 0; mt < 3; mt++) {
                const int o = g * 48 + mt * 16 + (lane & 15);
                bf16x8 af = *(const bf16x8*)(wso2 + (size_t)o * CH + c);
                #pragma unroll
                for (int nt = 0; nt < 4; nt++)
                    acc2[mt][nt] = __builtin_amdgcn_mfma_f32_16x16x32_bf16(af, bh[nt], acc2[mt][nt], 0, 0, 0);
            }
        }
        #pragma unroll
        for (int mt = 0; mt < 3; mt++) {
            const int o_base = g * 48 + mt * 16 + ((lane >> 4) << 2);
            float4 sb = *(const float4*)(so_b2 + o_base);
            #pragma unroll
            for (int nt = 0; nt < 4; nt++) {
                const int s = nt * 16 + (lane & 15);
                const float refx = (s & 7) * (1.f / 7.f);
                const float refy = (s >> 3) * (1.f / 7.f);
                auto mkp = [](float refc, float oc) {
                    float lc = fminf(fmaxf(refc + oc * 0.125f, 0.f), 1.f);
                    return fminf(fmaxf(lc * 8.f - 0.5f, 0.f), 7.f);
                };
                float4 out4;
                out4.x = mkp(refx, acc2[mt][nt][0] + sb.x);
                out4.y = mkp(refy, acc2[mt][nt][1] + sb.y);
                out4.z = mkp(refx, acc2[mt][nt][2] + sb.z);
                out4.w = mkp(refy, acc2[mt][nt][3] + sb.w);
                *(float4*)(PXY + (size_t)bw * 6144 + s * 96 + (o_base >> 1)) = out4;
            }
        }
    } else {
        // ---- conv2-aw (128->96) -> awS logits
        for (int mm = 0; mm < 2; mm++) {
            const int mtile = g + mm * 4;
            if (mtile >= 6) break;   // wave-uniform
            f32x4 acc3[4];
            #pragma unroll
            for (int nt = 0; nt < 4; nt++) acc3[nt] = (f32x4){0.f, 0.f, 0.f, 0.f};
            for (int ks = 0; ks < 4; ks++) {
                const int c = ks * 32 + kc;
                const int o = mtile * 16 + (lane & 15);
                bf16x8 af = *(const bf16x8*)(waw2 + (size_t)o * CH + c);
                #pragma unroll
                for (int nt = 0; nt < 4; nt++) {
                    bf16x8 bh = *(const bf16x8*)(hT + (nt * 16 + (lane & 15)) * HT_PAD + c);
                    acc3[nt] = __builtin_amdgcn_mfma_f32_16x16x32_bf16(af, bh, acc3[nt], 0, 0, 0);
                }
            }
            const int o_base = mtile * 16 + ((lane >> 4) << 2);
            float4 ab = *(const float4*)(aw_b2 + o_base);
            #pragma unroll
            for (int nt = 0; nt < 4; nt++) {
                const int s = nt * 16 + (lane & 15);
                float4 o4;
                o4.x = acc3[nt][0] + ab.x;
                o4.y = acc3[nt][1] + ab.y;
                o4.z = acc3[nt][2] + ab.z;
                o4.w = acc3[nt][3] + ab.w;
                *(float4*)(awS + s * AW_PAD + o_base) = o4;
            }
        }
        __syncthreads();
        // softmax over 12 per (s,h)
        for (int task = t; task < 512; task += 256) {
            const int s = task >> 3, h = task & 7;
            const float* row = awS + s * AW_PAD + h * 12;
            float4 r0 = *(const float4*)row;
            float4 r1 = *(const float4*)(row + 4);
            float4 r2 = *(const float4*)(row + 8);
            float v[12] = {r0.x, r0.y, r0.z, r0.w, r1.x, r1.y, r1.z, r1.w,
                           r2.x, r2.y, r2.z, r2.w};
            float m = v[0];
            #pragma unroll
            for (int j = 1; j < 12; j++) m = fmaxf(m, v[j]);
            float sum = 0.f;
            #pragma unroll
            for (int j = 0; j < 12; j++) { v[j] = __expf(v[j] - m); sum += v[j]; }
            float rinv = 1.f / sum;
            float* dst = A + (size_t)bw * 6144 + s * 96 + h * 12;
            float4 w0 = {v[0] * rinv, v[1] * rinv, v[2] * rinv, v[3] * rinv};
            float4 w1v = {v[4] * rinv, v[5] * rinv, v[6] * rinv, v[7] * rinv};
            float4 w2 = {v[8] * rinv, v[9] * rinv, v[10] * rinv, v[11] * rinv};
            *(float4*)dst = w0;
            *(float4*)(dst + 4) = w1v;
            *(float4*)(dst + 8) = w2;
        }
    }
}

// ---------------------------------------------------------------------------
// K2: per (window, level): stage + vp GEMM -> Vb bf16[s'][c] -> register
//     bilinear gather -> bf16 partial to POUT.
//   LDS: vsT[64][264]bf16 33792 + Vb[64][264]bf16 33792 = 67584 -> 2/CU.
// ---------------------------------------------------------------------------
__global__ __launch_bounds__(256, 2) void k_attn(
    const float* __restrict__ values,
    const unsigned short* __restrict__ wvp, const float* __restrict__ vp_b,
    const float* __restrict__ lemb,
    const float2* __restrict__ PXY, const float* __restrict__ A,
    unsigned short* __restrict__ POUT)
{
    extern __shared__ char smem[];
    unsigned short* vsT = (unsigned short*)smem;            // [64][264]
    unsigned short* Vb  = (unsigned short*)(smem + 33792);  // [64][264]

    const int bid = blockIdx.x;
    const int l   = bid >> 8;
    const int bw  = xcd_swz(bid & 255);
    const int b  = bw >> 6;
    const int wy = (bw >> 3) & 7;
    const int wx = bw & 7;
    const int t  = threadIdx.x;
    const int lane = t & 63;
    const int g  = rfl(t >> 6);
    const int kc = (lane >> 4) * 8;
    const int srow = (lane >> 3) * 64 + (lane & 7);
    const int sq = t >> 2;      // gather: spatial position
    const int dq = t & 3;       // gather: 8-channel slice within head

    // ---- stage vsT[s][c] bf16 (+ level embed)
    {
        const float* vb = values + ((size_t)(b * NLV + l) * CC) * 4096 + wy * 8 * 64 + wx * 8;
        const float* le = lemb + l * CC;
        for (int it = 0; it < 8; it++) {
            int cg = g * 8 + it;
            float tmp[8];
            #pragma unroll
            for (int j = 0; j < 8; j++) {
                int c = cg * 8 + j;
                tmp[j] = vb[(size_t)c * 4096 + srow] + le[c];
            }
            *(bf16x8*)(vsT + lane * VST_PAD + cg * 8) = pack8(tmp);
        }
    }
    __syncthreads();

    // ---- vp GEMM (m=o, n=s): wave g -> o in [g*64,+64); write Vb[s][o] bf16
    {
        f32x4 acc[4][4];
        #pragma unroll
        for (int mt = 0; mt < 4; mt++)
            #pragma unroll
            for (int nt = 0; nt < 4; nt++) acc[mt][nt] = (f32x4){0.f, 0.f, 0.f, 0.f};
        for (int ks = 0; ks < 8; ks++) {
            const int c = ks * 32 + kc;
            bf16x8 bf[4];
            #pragma unroll
            for (int nt = 0; nt < 4; nt++)
                bf[nt] = *(const bf16x8*)(vsT + (nt * 16 + (lane & 15)) * VST_PAD + c);
            #pragma unroll
            for (int mt = 0; mt < 4; mt++) {
                const int o = g * 64 + mt * 16 + (lane & 15);
                bf16x8 af = *(const bf16x8*)(wvp + (size_t)o * CC + c);
                #pragma unroll
                for (int nt = 0; nt < 4; nt++)
                    acc[mt][nt] = __builtin_amdgcn_mfma_f32_16x16x32_bf16(
                        af, bf[nt], acc[mt][nt], 0, 0, 0);
            }
        }
        #pragma unroll
        for (int mt = 0; mt < 4; mt++) {
            const int o0 = g * 64 + mt * 16 + ((lane >> 4) << 2);
            float4 bv = *(const float4*)(vp_b + o0);
            #pragma unroll
            for (int nt = 0; nt < 4; nt++) {
                const int s = nt * 16 + (lane & 15);
                bf16x4 pk;
                #pragma unroll
                for (int r = 0; r < 4; r++)
                    pk[r] = (short)f2bf(acc[mt][nt][r] + ((const float*)&bv)[r]);
                *(bf16x4*)(Vb + s * VLB_PAD + o0) = pk;
            }
        }
    }
    __syncthreads();

    // ---- bilinear gather, this level's 4 points; accumulate f32 in regs
    float outA[8][8];
    #pragma unroll
    for (int h = 0; h < 8; h++)
        #pragma unroll
        for (int j = 0; j < 8; j++) outA[h][j] = 0.f;
    {
        const float2* pxyp = PXY + (size_t)bw * 6144 + sq * 96;
        const float*  ap   = A   + (size_t)bw * 6144 + sq * 96;
        #pragma unroll
        for (int h = 0; h < 8; h++) {
            const int cb = h * 32 + dq * 8;
            #pragma unroll
            for (int p = 0; p < NPT; p++) {
                const int lp = l * NPT + p;
                float2 pxy = pxyp[h * 12 + lp];
                float  a   = ap[h * 12 + lp];
                float x0f = floorf(pxy.x), y0f = floorf(pxy.y);
                float fx = pxy.x - x0f, fy = pxy.y - y0f;
                int x0 = (int)x0f, y0 = (int)y0f;
                int x1 = min(x0 + 1, 7), y1 = min(y0 + 1, 7);
                float w00 = a * (1.f - fx) * (1.f - fy), w01 = a * fx * (1.f - fy);
                float w10 = a * (1.f - fx) * fy,         w11 = a * fx * fy;
                bf16x8 v00 = *(const bf16x8*)(Vb + (y0 * 8 + x0) * VLB_PAD + cb);
                bf16x8 v01 = *(const bf16x8*)(Vb + (y0 * 8 + x1) * VLB_PAD + cb);
                bf16x8 v10 = *(const bf16x8*)(Vb + (y1 * 8 + x0) * VLB_PAD + cb);
                bf16x8 v11 = *(const bf16x8*)(Vb + (y1 * 8 + x1) * VLB_PAD + cb);
                #pragma unroll
                for (int j = 0; j < 8; j++)
                    outA[h][j] = fmaf(w00, bf2f(v00[j]),
                                 fmaf(w01, bf2f(v01[j]),
                                 fmaf(w10, bf2f(v10[j]),
                                 fmaf(w11, bf2f(v11[j]), outA[h][j]))));
            }
        }
    }

    // ---- write bf16 partial: POUT[((bw*3+l)*64+s)*256 + c]
    {
        unsigned short* pout = POUT + (((size_t)(bw * 3 + l)) * 64 + sq) * 256;
        #pragma unroll
        for (int h = 0; h < 8; h++)
            *(bf16x8*)(pout + h * 32 + dq * 8) = pack8(outA[h]);
    }
}

// ---------------------------------------------------------------------------
// K3: sum 3 level-partials -> vsT bf16 -> op GEMM -> out (window reverse).
//   LDS: vsT[64][264]bf16 = 33792.
// ---------------------------------------------------------------------------
__global__ __launch_bounds__(256, 2) void k_out(
    const unsigned short* __restrict__ POUT,
    const unsigned short* __restrict__ wop, const float* __restrict__ op_b,
    float* __restrict__ outp)
{
    extern __shared__ char smem[];
    unsigned short* vsT = (unsigned short*)smem;   // [64][264]

    const int bw = xcd_swz(blockIdx.x);
    const int b  = bw >> 6;
    const int wy = (bw >> 3) & 7;
    const int wx = bw & 7;
    const int t  = threadIdx.x;
    const int lane = t & 63;
    const int g  = rfl(t >> 6);
    const int kc = (lane >> 4) * 8;

    // sum partials (8 chunks per thread)
    for (int j = t; j < 2048; j += 256) {
        const int s = j >> 5, cb = (j & 31) * 8;
        const unsigned short* base = POUT + (((size_t)bw * 3) * 64 + s) * 256 + cb;
        bf16x8 v0 = *(const bf16x8*)base;
        bf16x8 v1 = *(const bf16x8*)(base + 16384);
        bf16x8 v2 = *(const bf16x8*)(base + 32768);
        float o[8];
        #pragma unroll
        for (int i = 0; i < 8; i++) o[i] = bf2f(v0[i]) + bf2f(v1[i]) + bf2f(v2[i]);
        *(bf16x8*)(vsT + s * VST_PAD + cb) = pack8(o);
    }
    __syncthreads();

    // op GEMM (m=o, n=s) + bias + window-reverse store
    f32x4 acc[4][4];
    #pragma unroll
    for (int mt = 0; mt < 4; mt++)
        #pragma unroll
        for (int nt = 0; nt < 4; nt++) acc[mt][nt] = (f32x4){0.f, 0.f, 0.f, 0.f};
    for (int ks = 0; ks < 8; ks++) {
        const int c = ks * 32 + kc;
        bf16x8 bq[4];
        #pragma unroll
        for (int nt = 0; nt < 4; nt++)
            bq[nt] = *(const bf16x8*)(vsT + (nt * 16 + (lane & 15)) * VST_PAD + c);
        #pragma unroll
        for (int mt = 0; mt < 4; mt++) {
            const int o = g * 64 + mt * 16 + (lane & 15);
            bf16x8 af = *(const bf16x8*)(wop + (size_t)o * CC + c);
            #pragma unroll
            for (int nt = 0; nt < 4; nt++)
                acc[mt][nt] = __builtin_amdgcn_mfma_f32_16x16x32_bf16(
                    af, bq[nt], acc[mt][nt], 0, 0, 0);
        }
    }
    const size_t obase = (size_t)b * CC * 4096 + wy * 8 * 64 + wx * 8;
    #pragma unroll
    for (int mt = 0; mt < 4; mt++)
        #pragma unroll
        for (int nt = 0; nt < 4; nt++)
            #pragma unroll
            for (int r = 0; r < 4; r++) {
                int o = g * 64 + mt * 16 + (lane >> 4) * 4 + r;
                int s = nt * 16 + (lane & 15);
                outp[obase + (size_t)o * 4096 + (s >> 3) * 64 + (s & 7)]
                    = acc[mt][nt][r] + op_b[o];
            }
}

// ---------------------------------------------------------------------------
extern "C" void kernel_launch(void* const* d_in, const int* in_sizes, int n_in,
                              void* d_out, int out_size, void* d_ws, size_t ws_size,
                              hipStream_t stream)
{
    (void)in_sizes; (void)n_in; (void)out_size; (void)ws_size;
    const float* query = (const float*)d_in[0];
    const float* values = (const float*)d_in[2];
    const float* so_w1 = (const float*)d_in[3];
    const float* so_b1 = (const float*)d_in[4];
    const float* so_g  = (const float*)d_in[5];
    const float* so_be = (const float*)d_in[6];
    const float* so_w2 = (const float*)d_in[7];
    const float* so_b2 = (const float*)d_in[8];
    const float* aw_w1 = (const float*)d_in[9];
    const float* aw_b1 = (const float*)d_in[10];
    const float* aw_g  = (const float*)d_in[11];
    const float* aw_be = (const float*)d_in[12];
    const float* aw_w2 = (const float*)d_in[13];
    const float* aw_b2 = (const float*)d_in[14];
    const float* vp_w  = (const float*)d_in[15];
    const float* vp_b  = (const float*)d_in[16];
    const float* op_w  = (const float*)d_in[17];
    const float* op_b  = (const float*)d_in[18];
    const float* lemb  = (const float*)d_in[19];

    float2* PXY = (float2*)((char*)d_ws + WS_PXY);
    float*  A   = (float*)((char*)d_ws + WS_A);
    unsigned short* WB   = (unsigned short*)((char*)d_ws + WS_WB);
    unsigned short* POUT = (unsigned short*)((char*)d_ws + WS_POUT);
    float* outp = (float*)d_out;

    WPack p = {so_w1, aw_w1, so_w2, aw_w2, vp_w, op_w, WB};
    k_cvt<<<dim3((W_TOT / 8 + 255) / 256), dim3(256), 0, stream>>>(p);

    const int lds1 = 76800;
    const int lds2 = 67584;
    const int lds3 = 33792;
    hipFuncSetAttribute((const void*)k_heads, hipFuncAttributeMaxDynamicSharedMemorySize, lds1);
    hipFuncSetAttribute((const void*)k_attn,  hipFuncAttributeMaxDynamicSharedMemorySize, lds2);
    hipFuncSetAttribute((const void*)k_out,   hipFuncAttributeMaxDynamicSharedMemorySize, lds3);

    k_heads<<<dim3(NWIN * 2), dim3(256), lds1, stream>>>(
        query, WB + W_SO1, so_b1, so_g, so_be, WB + W_SO2, so_b2,
        WB + W_AW1, aw_b1, aw_g, aw_be, WB + W_AW2, aw_b2, PXY, A);
    k_attn<<<dim3(NWIN * 3), dim3(256), lds2, stream>>>(
        values, WB + W_VP, vp_b, lemb, PXY, A, POUT);
    k_out<<<dim3(NWIN), dim3(256), lds3, stream>>>(
        POUT, WB + W_OP, op_b, outp);
}